// Round 7
// baseline (772.892 us; speedup 1.0000x reference)
//
#include <hip/hip_runtime.h>

typedef unsigned short u16;
typedef __attribute__((ext_vector_type(8))) short short8;
typedef __attribute__((ext_vector_type(4))) float f32x4;

static __device__ __forceinline__ float bf2f(u16 u) {
    union { unsigned int u; float f; } c; c.u = ((unsigned int)u) << 16; return c.f;
}
static __device__ __forceinline__ u16 f2bf(float f) {
    union { float f; unsigned int u; } c; c.f = f;
    unsigned int r = (c.u + 0x7fffu + ((c.u >> 16) & 1u)) >> 16;
    return (u16)r;
}

// async 16B global -> LDS (wave-uniform base + lane*16)
static __device__ __forceinline__ void glds16(const u16* g, u16* l) {
    __builtin_amdgcn_global_load_lds((const __attribute__((address_space(1))) unsigned int*)g,
                                     (__attribute__((address_space(3))) unsigned int*)l,
                                     16, 0, 0);
}

// fast GELU: tanh-form, gelu(t) = t * sigmoid(2u), u = 0.79788456t(1+0.044715t^2)
// |err vs exact erf-gelu| <= ~3e-4 on |t|<6 — far below bf16 rounding of outputs.
// ~8 VALU ops (1 v_exp) vs ~25-30 for erff.  [r6: FF1 VALUBusy 57% -> 16.6%, -39us]
static __device__ __forceinline__ float gelu_fast(float t) {
    float u2 = 1.5957691216f * t * (1.0f + 0.044715f * t * t);  // 2*sqrt(2/pi)*...
    float e = __expf(u2);
    return __fdividef(t * e, e + 1.0f);
}

// ---------------- all weight transposes in ONE kernel -----------------------
// fp32 W(K,N) -> bf16 Wt(N,K), 32x32 tiles. id ranges: [0,3072) Wq|Wk|Wv packed,
// [3072,4096) Wo, [4096,8192) W1, [8192,12288) W2.
__global__ void wtrans_all(const float* __restrict__ q, const float* __restrict__ k,
                           const float* __restrict__ v, const float* __restrict__ o,
                           const float* __restrict__ w1, const float* __restrict__ w2,
                           u16* __restrict__ tqkv, u16* __restrict__ to_,
                           u16* __restrict__ t1, u16* __restrict__ t2) {
    const int id = blockIdx.x;
    const float* W; u16* D; int K, N, local;
    if (id < 3072) {
        const int which = id >> 10; local = id & 1023;
        W = which == 0 ? q : (which == 1 ? k : v);
        D = tqkv + (size_t)which * 1024 * 1024; K = 1024; N = 1024;
    } else if (id < 4096) { W = o;  D = to_; K = 1024; N = 1024; local = id - 3072; }
    else if (id < 8192)   { W = w1; D = t1;  K = 1024; N = 4096; local = id - 4096; }
    else                  { W = w2; D = t2;  K = 4096; N = 1024; local = id - 8192; }
    const int nx = N / 32;
    const int n0 = (local % nx) * 32, k0 = (local / nx) * 32;
    __shared__ float t[32][33];
    for (int i = threadIdx.y; i < 32; i += 8)
        t[i][threadIdx.x] = W[(size_t)(k0 + i) * N + n0 + threadIdx.x];
    __syncthreads();
    for (int i = threadIdx.y; i < 32; i += 8)
        D[(size_t)(n0 + i) * K + k0 + threadIdx.x] = f2bf(t[threadIdx.x][i]);
}

// ---------------- layernorm (fp32 or bf16 input) -> bf16 --------------------
template <typename TI>
__global__ __launch_bounds__(256) void ln_kernel(const TI* __restrict__ x,
                                                 const float* __restrict__ g,
                                                 const float* __restrict__ b,
                                                 u16* __restrict__ out) {
    const int row = blockIdx.x;
    float4 v;
    if constexpr (sizeof(TI) == 4) {
        v = ((const float4*)((const float*)x + (size_t)row * 1024))[threadIdx.x];
    } else {
        ushort4 u = ((const ushort4*)((const u16*)x + (size_t)row * 1024))[threadIdx.x];
        v = make_float4(bf2f(u.x), bf2f(u.y), bf2f(u.z), bf2f(u.w));
    }
    float s = v.x + v.y + v.z + v.w;
    float ss = v.x * v.x + v.y * v.y + v.z * v.z + v.w * v.w;
    #pragma unroll
    for (int o = 32; o; o >>= 1) { s += __shfl_down(s, o); ss += __shfl_down(ss, o); }
    __shared__ float red[8];
    const int lane = threadIdx.x & 63, wave = threadIdx.x >> 6;
    if (lane == 0) { red[wave] = s; red[4 + wave] = ss; }
    __syncthreads();
    float S = red[0] + red[1] + red[2] + red[3];
    float SS = red[4] + red[5] + red[6] + red[7];
    float mu = S * (1.0f / 1024.0f);
    float var = SS * (1.0f / 1024.0f) - mu * mu;
    float rs = rsqrtf(var + 1e-5f);
    float4 gv = ((const float4*)g)[threadIdx.x];
    float4 bv = ((const float4*)b)[threadIdx.x];
    ushort4 o4;
    o4.x = f2bf((v.x - mu) * rs * gv.x + bv.x);
    o4.y = f2bf((v.y - mu) * rs * gv.y + bv.y);
    o4.z = f2bf((v.z - mu) * rs * gv.z + bv.z);
    o4.w = f2bf((v.w - mu) * rs * gv.w + bv.w);
    ((ushort4*)(out + (size_t)row * 1024))[threadIdx.x] = o4;
}

// ---------------- per-token attention: one token per WAVE -------------------
// QKV packed per token: row stride 3072 (Q at +0, K at +1024, V at +2048).
__global__ __launch_bounds__(256) void attn_kernel(const u16* __restrict__ QKV,
                                                   const float* __restrict__ unc,
                                                   u16* __restrict__ out) {
    __shared__ float kb[4][1024];  // [wave][j*16+h]
    __shared__ float vb[4][1024];
    const int tid = threadIdx.x;
    const int wave = tid >> 6, lane = tid & 63;
    const int tok = blockIdx.x * 4 + wave;
    const size_t baseq = (size_t)tok * 3072;

    #pragma unroll
    for (int e2 = 0; e2 < 2; e2++) {
        const int c = lane + 64 * e2;
        const int h = c >> 3, j0 = (c & 7) * 8;
        uint4 kraw = *(const uint4*)(QKV + baseq + 1024 + c * 8);
        uint4 vraw = *(const uint4*)(QKV + baseq + 2048 + c * 8);
        u16 kt[8], vt[8];
        *(uint4*)kt = kraw; *(uint4*)vt = vraw;
        #pragma unroll
        for (int e = 0; e < 8; e++) {
            kb[wave][(j0 + e) * 16 + h] = bf2f(kt[e]);
            vb[wave][(j0 + e) * 16 + h] = bf2f(vt[e]);
        }
    }
    float q[16];
    #pragma unroll
    for (int h = 0; h < 16; h++) q[h] = bf2f(QKV[baseq + h * 64 + lane]);
    float su = 0.0f;
    #pragma unroll
    for (int h = 0; h < 16; h++) su += unc[h];
    const float sinv = 1.0f / (8.0f * su);  // sqrt(64) * sum(u)
    __syncthreads();

    float s[64];
    #pragma unroll
    for (int j = 0; j < 64; j++) {
        const float4* kr = (const float4*)&kb[wave][j * 16];
        float4 k0 = kr[0], k1 = kr[1], k2 = kr[2], k3 = kr[3];
        float a = q[0] * k0.x + q[1] * k0.y + q[2] * k0.z + q[3] * k0.w;
        a += q[4] * k1.x + q[5] * k1.y + q[6] * k1.z + q[7] * k1.w;
        a += q[8] * k2.x + q[9] * k2.y + q[10] * k2.z + q[11] * k2.w;
        a += q[12] * k3.x + q[13] * k3.y + q[14] * k3.z + q[15] * k3.w;
        s[j] = a;
    }
    float m = s[0];
    #pragma unroll
    for (int j = 1; j < 64; j++) m = fmaxf(m, s[j]);
    float sum = 0.0f;
    #pragma unroll
    for (int j = 0; j < 64; j++) { s[j] = __expf((s[j] - m) * sinv); sum += s[j]; }
    const float r = 1.0f / sum;
    float o[16];
    #pragma unroll
    for (int h = 0; h < 16; h++) o[h] = 0.0f;
    #pragma unroll
    for (int j = 0; j < 64; j++) {
        const float p = s[j];
        const float4* vr = (const float4*)&vb[wave][j * 16];
        float4 v0 = vr[0], v1 = vr[1], v2 = vr[2], v3 = vr[3];
        o[0] += p * v0.x; o[1] += p * v0.y; o[2] += p * v0.z; o[3] += p * v0.w;
        o[4] += p * v1.x; o[5] += p * v1.y; o[6] += p * v1.z; o[7] += p * v1.w;
        o[8] += p * v2.x; o[9] += p * v2.y; o[10] += p * v2.z; o[11] += p * v2.w;
        o[12] += p * v3.x; o[13] += p * v3.y; o[14] += p * v3.z; o[15] += p * v3.w;
    }
    const size_t baso = (size_t)tok * 1024;
    #pragma unroll
    for (int h = 0; h < 16; h++) out[baso + h * 64 + lane] = f2bf(o[h] * r);
}

// ---------------- bf16 GEMM: C[M,N] = A[M,K] * Bt[N,K]^T --------------------
// Proven 128x128 structure. BK=64 K-loop, async glds staging, XOR-swizzled LDS
// (conflict-free b128 reads, SQ_LDS_BANK_CONFLICT=0 measured).
// PF=false (K=1024 ops, cache-warm staging): 2-barrier loop, 32KB LDS, lb(256,4).
// PF=true  (FF2, K=4096: A = 128MB FF1 product, HBM-latency staging; r6 showed
//   44% of cycles on neither pipe = vmcnt drain): double-buffered prefetch —
//   issue tile t+1's glds BEFORE computing tile t; single __syncthreads per iter
//   (its implicit vmcnt(0) drains AFTER the MFMA phase -> latency hidden).
//   64KB LDS -> lb(256,2). Race-safe: buf^1's prior readers completed ds_reads
//   before the previous barrier (MFMA operand consumption forces lgkm waits).
// EPI 0: bf16(acc) -> outB
// EPI 1: fp32  acc+bias+bf16res -> outF
// EPI 2: bf16(gelu_fast(acc+bias)) -> outB
// EPI 3: bf16(acc+bias+fp32res) -> outB
template <int EPI, bool PF>
__global__ __launch_bounds__(256, PF ? 2 : 4)
void gemm_kernel(const u16* __restrict__ A, const u16* __restrict__ Bt,
                 const float* __restrict__ bias, const void* __restrict__ res,
                 float* __restrict__ outF, u16* __restrict__ outB,
                 int N, int K) {
    __shared__ __align__(16) u16 As[(PF ? 2 : 1) * 128 * 64];
    __shared__ __align__(16) u16 Bs[(PF ? 2 : 1) * 128 * 64];
    const int tid = threadIdx.x;
    const int lane = tid & 63;
    const int wave = tid >> 6;
    const int wm = (wave >> 1) * 64;
    const int wn = (wave & 1) * 64;
    const int m0 = blockIdx.x * 128;
    const int n0 = blockIdx.y * 128;

    f32x4 acc[4][4];
    #pragma unroll
    for (int i = 0; i < 4; i++)
        #pragma unroll
        for (int j = 0; j < 4; j++) acc[i][j] = (f32x4){0.f, 0.f, 0.f, 0.f};

    // staging: 1024 chunks of 16B per matrix; thread handles c = tid + 256e
    const u16* aP[4];
    const u16* bP[4];
    #pragma unroll
    for (int e = 0; e < 4; e++) {
        const int c = tid + 256 * e;
        const int r = c >> 3;
        const int qg = (c & 7) ^ (r & 7);
        aP[e] = A + (size_t)(m0 + r) * K + qg * 8;
        bP[e] = Bt + (size_t)(n0 + r) * K + qg * 8;
    }

    if constexpr (PF) {
        // ---- 2-phase prefetch path (T3 minimal recipe) ----
        const int NT = K >> 6;
        #pragma unroll
        for (int e = 0; e < 4; e++) {        // prologue: tile 0 -> half 0
            glds16(aP[e], &As[(tid + 256 * e) * 8]);
            glds16(bP[e], &Bs[(tid + 256 * e) * 8]);
        }
        __syncthreads();                     // vmcnt(0)+barrier: tile 0 ready
        int cur = 0;
        for (int t = 0; t < NT; ++t) {
            const int nxt = cur ^ 1;
            if (t + 1 < NT) {
                const int ko = (t + 1) * 64;
                #pragma unroll
                for (int e = 0; e < 4; e++) {    // issue-only; drained at the
                    glds16(aP[e] + ko, &As[nxt * 8192 + (tid + 256 * e) * 8]);
                    glds16(bP[e] + ko, &Bs[nxt * 8192 + (tid + 256 * e) * 8]);
                }
            }
            const int cb = cur * 8192;
            #pragma unroll
            for (int kk = 0; kk < 2; kk++) {
                const int Q = (lane >> 4) + kk * 4;
                short8 af[4], bf[4];
                #pragma unroll
                for (int i = 0; i < 4; i++) {
                    const int R = wm + i * 16 + (lane & 15);
                    af[i] = *(const short8*)&As[cb + R * 64 + ((Q ^ (R & 7)) * 8)];
                }
                #pragma unroll
                for (int j = 0; j < 4; j++) {
                    const int R = wn + j * 16 + (lane & 15);
                    bf[j] = *(const short8*)&Bs[cb + R * 64 + ((Q ^ (R & 7)) * 8)];
                }
                #pragma unroll
                for (int i = 0; i < 4; i++)
                    #pragma unroll
                    for (int j = 0; j < 4; j++)
                        acc[i][j] = __builtin_amdgcn_mfma_f32_16x16x32_bf16(af[i], bf[j], acc[i][j], 0, 0, 0);
            }
            __syncthreads();   // drains prefetch vmcnt AFTER compute; guards swap
            cur = nxt;
        }
    } else {
        // ---- proven 2-barrier path ----
        for (int k0 = 0; k0 < K; k0 += 64) {
            __syncthreads();  // prior iter's ds_reads done before async overwrite
            #pragma unroll
            for (int e = 0; e < 4; e++) {
                glds16(aP[e] + k0, &As[(tid + 256 * e) * 8]);
                glds16(bP[e] + k0, &Bs[(tid + 256 * e) * 8]);
            }
            __syncthreads();  // vmcnt drained at barrier => LDS tile valid
            #pragma unroll
            for (int kk = 0; kk < 2; kk++) {
                const int Q = (lane >> 4) + kk * 4;
                short8 af[4], bf[4];
                #pragma unroll
                for (int i = 0; i < 4; i++) {
                    const int R = wm + i * 16 + (lane & 15);
                    af[i] = *(const short8*)&As[R * 64 + ((Q ^ (R & 7)) * 8)];
                }
                #pragma unroll
                for (int j = 0; j < 4; j++) {
                    const int R = wn + j * 16 + (lane & 15);
                    bf[j] = *(const short8*)&Bs[R * 64 + ((Q ^ (R & 7)) * 8)];
                }
                #pragma unroll
                for (int i = 0; i < 4; i++)
                    #pragma unroll
                    for (int j = 0; j < 4; j++)
                        acc[i][j] = __builtin_amdgcn_mfma_f32_16x16x32_bf16(af[i], bf[j], acc[i][j], 0, 0, 0);
            }
        }
    }

    const int rbase = (lane >> 4) * 4;
    const int cidx = lane & 15;
    #pragma unroll
    for (int i = 0; i < 4; i++) {
        #pragma unroll
        for (int j = 0; j < 4; j++) {
            const int n = n0 + wn + j * 16 + cidx;
            #pragma unroll
            for (int r = 0; r < 4; r++) {
                const int m = m0 + wm + i * 16 + rbase + r;
                const size_t idx = (size_t)m * N + n;
                float v = acc[i][j][r];
                if (EPI == 0) {
                    outB[idx] = f2bf(v);
                } else if (EPI == 1) {
                    outF[idx] = v + bias[n] + bf2f(((const u16*)res)[idx]);
                } else if (EPI == 2) {
                    outB[idx] = f2bf(gelu_fast(v + bias[n]));
                } else {
                    outB[idx] = f2bf(v + bias[n] + ((const float*)res)[idx]);
                }
            }
        }
    }
}

extern "C" void kernel_launch(void* const* d_in, const int* in_sizes, int n_in,
                              void* d_out, int out_size, void* d_ws, size_t ws_size,
                              hipStream_t stream) {
    const float* x    = (const float*)d_in[0];
    const float* unc  = (const float*)d_in[1];
    const float* Wq   = (const float*)d_in[2];
    const float* Wk   = (const float*)d_in[3];
    const float* Wv   = (const float*)d_in[4];
    const float* Wo   = (const float*)d_in[5];
    const float* bo   = (const float*)d_in[6];
    const float* ln1g = (const float*)d_in[7];
    const float* ln1b = (const float*)d_in[8];
    const float* ln2g = (const float*)d_in[9];
    const float* ln2b = (const float*)d_in[10];
    const float* W1   = (const float*)d_in[11];
    const float* b1   = (const float*)d_in[12];
    const float* W2   = (const float*)d_in[13];
    const float* b2   = (const float*)d_in[14];
    float* out = (float*)d_out;

    const int M = 16384;  // 4 * 4096 tokens
    char* ws = (char*)d_ws;
    const size_t MB = 1024ull * 1024ull;
    u16* Wqkv = (u16*)(ws + 0 * MB);    // [3072][1024] bf16: Wq^T | Wk^T | Wv^T
    u16* Wto  = (u16*)(ws + 6 * MB);
    u16* Wt1  = (u16*)(ws + 8 * MB);    // [4096][1024]
    u16* Wt2  = (u16*)(ws + 16 * MB);   // [1024][4096]
    u16* Abuf = (u16*)(ws + 24 * MB);   // 16384x1024 bf16 (tmp / attn-out / tmp2)
    u16* QKVb = (u16*)(ws + 56 * MB);   // 16384x3072 bf16 = 96MB (dead after attn)
    u16* Xr   = (u16*)(ws + 56 * MB);   // bf16 residual x2, 32MB (overwrites dead QKVb)
    u16* FF1  = (u16*)(ws + 88 * MB);   // full: 16384x4096 bf16 = 128MB (-> 216MB)
                                        // fallback: 8192x4096 = 64MB (-> 152MB)

    wtrans_all<<<12288, dim3(32, 8), 0, stream>>>(Wq, Wk, Wv, Wo, W1, W2,
                                                  Wqkv, Wto, Wt1, Wt2);

    ln_kernel<float><<<M, 256, 0, stream>>>(x, ln1g, ln1b, Abuf);

    // fused QKV projection: C[16384][3072]
    gemm_kernel<0, false><<<dim3(128, 24), 256, 0, stream>>>(Abuf, Wqkv, nullptr, nullptr,
                                                             nullptr, QKVb, 3072, 1024);

    attn_kernel<<<M / 4, 256, 0, stream>>>(QKVb, unc, Abuf);

    // Wo projection + bo + residual(x fp32) -> bf16 x2 (Xr)
    gemm_kernel<3, false><<<dim3(128, 8), 256, 0, stream>>>(Abuf, Wto, bo, x, nullptr, Xr, 1024, 1024);

    ln_kernel<u16><<<M, 256, 0, stream>>>(Xr, ln2g, ln2b, Abuf);

    if (ws_size >= 216ull * MB) {
        // full-M FF
        gemm_kernel<2, false><<<dim3(128, 32), 256, 0, stream>>>(Abuf, Wt1, b1, nullptr,
                                                                 nullptr, FF1, 4096, 1024);
        // FF2: K=4096, HBM-streamed A -> prefetch path
        gemm_kernel<1, true><<<dim3(128, 8), 256, 0, stream>>>(FF1, Wt2, b2, Xr,
                                                               out, nullptr, 1024, 4096);
    } else {
        // chunked fallback (152MB-proven map from round 0)
        for (int c = 0; c < 2; c++) {
            const size_t ro = (size_t)c * 8192;
            gemm_kernel<2, false><<<dim3(64, 32), 256, 0, stream>>>(Abuf + ro * 1024, Wt1, b1, nullptr,
                                                                    nullptr, FF1, 4096, 1024);
            gemm_kernel<1, true><<<dim3(64, 8), 256, 0, stream>>>(FF1, Wt2, b2, Xr + ro * 1024,
                                                                  out + ro * 1024, nullptr, 1024, 4096);
        }
    }
}

// Round 8
// 684.195 us; speedup vs baseline: 1.1296x; 1.1296x over previous
//
#include <hip/hip_runtime.h>

typedef unsigned short u16;
typedef __attribute__((ext_vector_type(8))) short short8;
typedef __attribute__((ext_vector_type(4))) float f32x4;

static __device__ __forceinline__ float bf2f(u16 u) {
    union { unsigned int u; float f; } c; c.u = ((unsigned int)u) << 16; return c.f;
}
static __device__ __forceinline__ u16 f2bf(float f) {
    union { float f; unsigned int u; } c; c.f = f;
    unsigned int r = (c.u + 0x7fffu + ((c.u >> 16) & 1u)) >> 16;
    return (u16)r;
}

// async 16B global -> LDS (wave-uniform base + lane*16)
static __device__ __forceinline__ void glds16(const u16* g, u16* l) {
    __builtin_amdgcn_global_load_lds((const __attribute__((address_space(1))) unsigned int*)g,
                                     (__attribute__((address_space(3))) unsigned int*)l,
                                     16, 0, 0);
}

// fast GELU: tanh-form, gelu(t) = t * sigmoid(2u), u = 0.79788456t(1+0.044715t^2)
// |err vs exact erf-gelu| <= ~3e-4 on |t|<6 — far below bf16 rounding of outputs.
// ~8 VALU ops (1 v_exp) vs ~25-30 for erff.  [r6: FF1 VALUBusy 57% -> 16.6%, -39us]
static __device__ __forceinline__ float gelu_fast(float t) {
    float u2 = 1.5957691216f * t * (1.0f + 0.044715f * t * t);  // 2*sqrt(2/pi)*...
    float e = __expf(u2);
    return __fdividef(t * e, e + 1.0f);
}

// ---------------- all weight transposes in ONE kernel -----------------------
// fp32 W(K,N) -> bf16 Wt(N,K), 32x32 tiles. id ranges: [0,3072) Wq|Wk|Wv packed,
// [3072,4096) Wo, [4096,8192) W1, [8192,12288) W2.
__global__ void wtrans_all(const float* __restrict__ q, const float* __restrict__ k,
                           const float* __restrict__ v, const float* __restrict__ o,
                           const float* __restrict__ w1, const float* __restrict__ w2,
                           u16* __restrict__ tqkv, u16* __restrict__ to_,
                           u16* __restrict__ t1, u16* __restrict__ t2) {
    const int id = blockIdx.x;
    const float* W; u16* D; int K, N, local;
    if (id < 3072) {
        const int which = id >> 10; local = id & 1023;
        W = which == 0 ? q : (which == 1 ? k : v);
        D = tqkv + (size_t)which * 1024 * 1024; K = 1024; N = 1024;
    } else if (id < 4096) { W = o;  D = to_; K = 1024; N = 1024; local = id - 3072; }
    else if (id < 8192)   { W = w1; D = t1;  K = 1024; N = 4096; local = id - 4096; }
    else                  { W = w2; D = t2;  K = 4096; N = 1024; local = id - 8192; }
    const int nx = N / 32;
    const int n0 = (local % nx) * 32, k0 = (local / nx) * 32;
    __shared__ float t[32][33];
    for (int i = threadIdx.y; i < 32; i += 8)
        t[i][threadIdx.x] = W[(size_t)(k0 + i) * N + n0 + threadIdx.x];
    __syncthreads();
    for (int i = threadIdx.y; i < 32; i += 8)
        D[(size_t)(n0 + i) * K + k0 + threadIdx.x] = f2bf(t[threadIdx.x][i]);
}

// ---------------- layernorm (fp32 or bf16 input) -> bf16 --------------------
template <typename TI>
__global__ __launch_bounds__(256) void ln_kernel(const TI* __restrict__ x,
                                                 const float* __restrict__ g,
                                                 const float* __restrict__ b,
                                                 u16* __restrict__ out) {
    const int row = blockIdx.x;
    float4 v;
    if constexpr (sizeof(TI) == 4) {
        v = ((const float4*)((const float*)x + (size_t)row * 1024))[threadIdx.x];
    } else {
        ushort4 u = ((const ushort4*)((const u16*)x + (size_t)row * 1024))[threadIdx.x];
        v = make_float4(bf2f(u.x), bf2f(u.y), bf2f(u.z), bf2f(u.w));
    }
    float s = v.x + v.y + v.z + v.w;
    float ss = v.x * v.x + v.y * v.y + v.z * v.z + v.w * v.w;
    #pragma unroll
    for (int o = 32; o; o >>= 1) { s += __shfl_down(s, o); ss += __shfl_down(ss, o); }
    __shared__ float red[8];
    const int lane = threadIdx.x & 63, wave = threadIdx.x >> 6;
    if (lane == 0) { red[wave] = s; red[4 + wave] = ss; }
    __syncthreads();
    float S = red[0] + red[1] + red[2] + red[3];
    float SS = red[4] + red[5] + red[6] + red[7];
    float mu = S * (1.0f / 1024.0f);
    float var = SS * (1.0f / 1024.0f) - mu * mu;
    float rs = rsqrtf(var + 1e-5f);
    float4 gv = ((const float4*)g)[threadIdx.x];
    float4 bv = ((const float4*)b)[threadIdx.x];
    ushort4 o4;
    o4.x = f2bf((v.x - mu) * rs * gv.x + bv.x);
    o4.y = f2bf((v.y - mu) * rs * gv.y + bv.y);
    o4.z = f2bf((v.z - mu) * rs * gv.z + bv.z);
    o4.w = f2bf((v.w - mu) * rs * gv.w + bv.w);
    ((ushort4*)(out + (size_t)row * 1024))[threadIdx.x] = o4;
}

// ---------------- per-token attention: one token per WAVE -------------------
// QKV packed per token: row stride 3072 (Q at +0, K at +1024, V at +2048).
__global__ __launch_bounds__(256) void attn_kernel(const u16* __restrict__ QKV,
                                                   const float* __restrict__ unc,
                                                   u16* __restrict__ out) {
    __shared__ float kb[4][1024];  // [wave][j*16+h]
    __shared__ float vb[4][1024];
    const int tid = threadIdx.x;
    const int wave = tid >> 6, lane = tid & 63;
    const int tok = blockIdx.x * 4 + wave;
    const size_t baseq = (size_t)tok * 3072;

    #pragma unroll
    for (int e2 = 0; e2 < 2; e2++) {
        const int c = lane + 64 * e2;
        const int h = c >> 3, j0 = (c & 7) * 8;
        uint4 kraw = *(const uint4*)(QKV + baseq + 1024 + c * 8);
        uint4 vraw = *(const uint4*)(QKV + baseq + 2048 + c * 8);
        u16 kt[8], vt[8];
        *(uint4*)kt = kraw; *(uint4*)vt = vraw;
        #pragma unroll
        for (int e = 0; e < 8; e++) {
            kb[wave][(j0 + e) * 16 + h] = bf2f(kt[e]);
            vb[wave][(j0 + e) * 16 + h] = bf2f(vt[e]);
        }
    }
    float q[16];
    #pragma unroll
    for (int h = 0; h < 16; h++) q[h] = bf2f(QKV[baseq + h * 64 + lane]);
    float su = 0.0f;
    #pragma unroll
    for (int h = 0; h < 16; h++) su += unc[h];
    const float sinv = 1.0f / (8.0f * su);  // sqrt(64) * sum(u)
    __syncthreads();

    float s[64];
    #pragma unroll
    for (int j = 0; j < 64; j++) {
        const float4* kr = (const float4*)&kb[wave][j * 16];
        float4 k0 = kr[0], k1 = kr[1], k2 = kr[2], k3 = kr[3];
        float a = q[0] * k0.x + q[1] * k0.y + q[2] * k0.z + q[3] * k0.w;
        a += q[4] * k1.x + q[5] * k1.y + q[6] * k1.z + q[7] * k1.w;
        a += q[8] * k2.x + q[9] * k2.y + q[10] * k2.z + q[11] * k2.w;
        a += q[12] * k3.x + q[13] * k3.y + q[14] * k3.z + q[15] * k3.w;
        s[j] = a;
    }
    float m = s[0];
    #pragma unroll
    for (int j = 1; j < 64; j++) m = fmaxf(m, s[j]);
    float sum = 0.0f;
    #pragma unroll
    for (int j = 0; j < 64; j++) { s[j] = __expf((s[j] - m) * sinv); sum += s[j]; }
    const float r = 1.0f / sum;
    float o[16];
    #pragma unroll
    for (int h = 0; h < 16; h++) o[h] = 0.0f;
    #pragma unroll
    for (int j = 0; j < 64; j++) {
        const float p = s[j];
        const float4* vr = (const float4*)&vb[wave][j * 16];
        float4 v0 = vr[0], v1 = vr[1], v2 = vr[2], v3 = vr[3];
        o[0] += p * v0.x; o[1] += p * v0.y; o[2] += p * v0.z; o[3] += p * v0.w;
        o[4] += p * v1.x; o[5] += p * v1.y; o[6] += p * v1.z; o[7] += p * v1.w;
        o[8] += p * v2.x; o[9] += p * v2.y; o[10] += p * v2.z; o[11] += p * v2.w;
        o[12] += p * v3.x; o[13] += p * v3.y; o[14] += p * v3.z; o[15] += p * v3.w;
    }
    const size_t baso = (size_t)tok * 1024;
    #pragma unroll
    for (int h = 0; h < 16; h++) out[baso + h * 64 + lane] = f2bf(o[h] * r);
}

// ---------------- bf16 GEMM: C[M,N] = A[M,K] * Bt[N,K]^T --------------------
// Proven 128x128 structure (r6: QKV/FF1 ~46/39% MfmaUtil, bank conflicts 0).
// BK=64 K-loop, async glds staging, XOR-swizzled LDS, lb(256,4).
// r7 POST-MORTEM: PF double-buffer variant REVERTED — 64KB LDS cut occupancy
// 35->22%, FF2 154->201us (m132-style occupancy-vs-pipeline net loss).
// EPI 0: bf16(acc) -> outB
// EPI 1: fp32  acc+bias+bf16res -> outF
// EPI 2: bf16(gelu_fast(acc+bias)) -> outB
// EPI 3: bf16(acc+bias+fp32res) -> outB
template <int EPI>
__global__ __launch_bounds__(256, 4)
void gemm_kernel(const u16* __restrict__ A, const u16* __restrict__ Bt,
                 const float* __restrict__ bias, const void* __restrict__ res,
                 float* __restrict__ outF, u16* __restrict__ outB,
                 int N, int K) {
    __shared__ __align__(16) u16 As[128 * 64];
    __shared__ __align__(16) u16 Bs[128 * 64];
    const int tid = threadIdx.x;
    const int lane = tid & 63;
    const int wave = tid >> 6;
    const int wm = (wave >> 1) * 64;
    const int wn = (wave & 1) * 64;
    const int m0 = blockIdx.x * 128;
    const int n0 = blockIdx.y * 128;

    f32x4 acc[4][4];
    #pragma unroll
    for (int i = 0; i < 4; i++)
        #pragma unroll
        for (int j = 0; j < 4; j++) acc[i][j] = (f32x4){0.f, 0.f, 0.f, 0.f};

    // staging: 1024 chunks of 16B per matrix; thread handles c = tid + 256e
    const u16* aP[4];
    const u16* bP[4];
    #pragma unroll
    for (int e = 0; e < 4; e++) {
        const int c = tid + 256 * e;
        const int r = c >> 3;
        const int qg = (c & 7) ^ (r & 7);
        aP[e] = A + (size_t)(m0 + r) * K + qg * 8;
        bP[e] = Bt + (size_t)(n0 + r) * K + qg * 8;
    }

    for (int k0 = 0; k0 < K; k0 += 64) {
        __syncthreads();  // prior iter's ds_reads done before async overwrite
        #pragma unroll
        for (int e = 0; e < 4; e++) {
            glds16(aP[e] + k0, &As[(tid + 256 * e) * 8]);
            glds16(bP[e] + k0, &Bs[(tid + 256 * e) * 8]);
        }
        __syncthreads();  // vmcnt drained at barrier => LDS tile valid
        #pragma unroll
        for (int kk = 0; kk < 2; kk++) {
            const int Q = (lane >> 4) + kk * 4;
            short8 af[4], bf[4];
            #pragma unroll
            for (int i = 0; i < 4; i++) {
                const int R = wm + i * 16 + (lane & 15);
                af[i] = *(const short8*)&As[R * 64 + ((Q ^ (R & 7)) * 8)];
            }
            #pragma unroll
            for (int j = 0; j < 4; j++) {
                const int R = wn + j * 16 + (lane & 15);
                bf[j] = *(const short8*)&Bs[R * 64 + ((Q ^ (R & 7)) * 8)];
            }
            #pragma unroll
            for (int i = 0; i < 4; i++)
                #pragma unroll
                for (int j = 0; j < 4; j++)
                    acc[i][j] = __builtin_amdgcn_mfma_f32_16x16x32_bf16(af[i], bf[j], acc[i][j], 0, 0, 0);
        }
    }

    const int rbase = (lane >> 4) * 4;
    const int cidx = lane & 15;
    #pragma unroll
    for (int i = 0; i < 4; i++) {
        #pragma unroll
        for (int j = 0; j < 4; j++) {
            const int n = n0 + wn + j * 16 + cidx;
            #pragma unroll
            for (int r = 0; r < 4; r++) {
                const int m = m0 + wm + i * 16 + rbase + r;
                const size_t idx = (size_t)m * N + n;
                float v = acc[i][j][r];
                if (EPI == 0) {
                    outB[idx] = f2bf(v);
                } else if (EPI == 1) {
                    outF[idx] = v + bias[n] + bf2f(((const u16*)res)[idx]);
                } else if (EPI == 2) {
                    outB[idx] = f2bf(gelu_fast(v + bias[n]));
                } else {
                    outB[idx] = f2bf(v + bias[n] + ((const float*)res)[idx]);
                }
            }
        }
    }
}

extern "C" void kernel_launch(void* const* d_in, const int* in_sizes, int n_in,
                              void* d_out, int out_size, void* d_ws, size_t ws_size,
                              hipStream_t stream) {
    const float* x    = (const float*)d_in[0];
    const float* unc  = (const float*)d_in[1];
    const float* Wq   = (const float*)d_in[2];
    const float* Wk   = (const float*)d_in[3];
    const float* Wv   = (const float*)d_in[4];
    const float* Wo   = (const float*)d_in[5];
    const float* bo   = (const float*)d_in[6];
    const float* ln1g = (const float*)d_in[7];
    const float* ln1b = (const float*)d_in[8];
    const float* ln2g = (const float*)d_in[9];
    const float* ln2b = (const float*)d_in[10];
    const float* W1   = (const float*)d_in[11];
    const float* b1   = (const float*)d_in[12];
    const float* W2   = (const float*)d_in[13];
    const float* b2   = (const float*)d_in[14];
    float* out = (float*)d_out;

    const int M = 16384;  // 4 * 4096 tokens
    char* ws = (char*)d_ws;
    const size_t MB = 1024ull * 1024ull;
    u16* Wqkv = (u16*)(ws + 0 * MB);    // [3072][1024] bf16: Wq^T | Wk^T | Wv^T
    u16* Wto  = (u16*)(ws + 6 * MB);
    u16* Wt1  = (u16*)(ws + 8 * MB);    // [4096][1024]
    u16* Wt2  = (u16*)(ws + 16 * MB);   // [1024][4096]
    u16* Abuf = (u16*)(ws + 24 * MB);   // 16384x1024 bf16 (tmp / attn-out / tmp2)
    u16* QKVb = (u16*)(ws + 56 * MB);   // 16384x3072 bf16 = 96MB (dead after attn)
    u16* Xr   = (u16*)(ws + 56 * MB);   // bf16 residual x2, 32MB (overwrites dead QKVb)
    u16* FF1  = (u16*)(ws + 88 * MB);   // 8192x4096 bf16 = 64MB per chunk (152MB map)
    // CHANGE vs r6 (the ONLY change): FF always chunked 2x8192 rows. Mechanism:
    // FF1-chunk output (64MB) stays L3-resident for the immediately-following
    // FF2-chunk read -> FF2 staging drain sits on L2/L3 latency (~200cy) not
    // HBM (~900cy). Evidence: r6 full-M FF2 FETCH=233MB (A missed L3);
    // r0(chunked,erff)=713 vs r5(full,erff)=733.

    wtrans_all<<<12288, dim3(32, 8), 0, stream>>>(Wq, Wk, Wv, Wo, W1, W2,
                                                  Wqkv, Wto, Wt1, Wt2);

    ln_kernel<float><<<M, 256, 0, stream>>>(x, ln1g, ln1b, Abuf);

    // fused QKV projection: C[16384][3072]
    gemm_kernel<0><<<dim3(128, 24), 256, 0, stream>>>(Abuf, Wqkv, nullptr, nullptr,
                                                      nullptr, QKVb, 3072, 1024);

    attn_kernel<<<M / 4, 256, 0, stream>>>(QKVb, unc, Abuf);

    // Wo projection + bo + residual(x fp32) -> bf16 x2 (Xr)
    gemm_kernel<3><<<dim3(128, 8), 256, 0, stream>>>(Abuf, Wto, bo, x, nullptr, Xr, 1024, 1024);

    ln_kernel<u16><<<M, 256, 0, stream>>>(Xr, ln2g, ln2b, Abuf);

    // FF in 2 chunks of 8192 rows (FF1 chunk output L3-hot for FF2 chunk)
    for (int c = 0; c < 2; c++) {
        const size_t ro = (size_t)c * 8192;
        gemm_kernel<2><<<dim3(64, 32), 256, 0, stream>>>(Abuf + ro * 1024, Wt1, b1, nullptr,
                                                         nullptr, FF1, 4096, 1024);
        gemm_kernel<1><<<dim3(64, 8), 256, 0, stream>>>(FF1, Wt2, b2, Xr + ro * 1024,
                                                        out + ro * 1024, nullptr, 1024, 4096);
    }
}